// Round 13
// baseline (196.471 us; speedup 1.0000x reference)
//
#include <hip/hip_runtime.h>

// Problem constants (from reference)
constexpr int COLS    = 8;
constexpr int BATCH   = 8192;
constexpr int D       = 128;
constexpr int NUM_EMB = 12;
constexpr int NPAIRS  = 28;

typedef float floatx4 __attribute__((ext_vector_type(4)));

__device__ __forceinline__ floatx4 ld4(const float* p) {
    return *reinterpret_cast<const floatx4*>(p);
}
__device__ __forceinline__ void st4(float* p, floatx4 v) {
    *reinterpret_cast<floatx4*>(p) = v;
}
__device__ __forceinline__ float softplus01(float x) {
    return 0.01f * ((x > 15.0f) ? x : log1pf(expf(x)));
}
__device__ __forceinline__ float dot4(floatx4 a, floatx4 b) {
    return fmaf(a.x, b.x, fmaf(a.y, b.y, fmaf(a.z, b.z, a.w * b.w)));
}

// ===== Main kernel: byte-identical to R10 (54.7 us best) =====
__global__ __launch_bounds__(512, 4) void dsnas_kernel(
    const int*   __restrict__ features,   // [COLS, BATCH]
    const float* __restrict__ emb_mean,   // [COLS, NUM_EMB, D]
    const float* __restrict__ emb_std,    // [COLS, NUM_EMB, D]
    const float* __restrict__ W_nc,       // [NPAIRS, 4, 2, D]
    const float* __restrict__ W_cat,      // [NPAIRS, 2, 2*D]
    const float* __restrict__ log_alpha,  // [NPAIRS, 5]
    const float* __restrict__ noise,      // [NPAIRS, 2, BATCH, D]
    float*       __restrict__ out)        // [BATCH, 2]
{
    __shared__ float wlds[NPAIRS * 512];
    __shared__ int   pos_s[NPAIRS];

    const int tid = threadIdx.x;

    if (tid < NPAIRS) {
        const float* la = log_alpha + tid * 5;
        float best = la[0];
        int   bi   = 0;
        #pragma unroll
        for (int t = 1; t < 5; ++t) {
            float v = la[t];
            if (v > best) { best = v; bi = t; }
        }
        pos_s[tid] = bi;
    }
    __syncthreads();

    #pragma unroll
    for (int r = 0; r < 7; ++r) {
        const int idx = tid + r * 512;
        const int k   = idx >> 7;
        const int f   = idx & 127;
        const int row = f >> 5;
        const int c4  = f & 31;
        const int s   = pos_s[k];
        floatx4 v = {0.0f, 0.0f, 0.0f, 0.0f};
        if (s == 4) {
            v = ld4(W_cat + (size_t)k * 512 + f * 4);
        } else if ((row & 1) == 0) {
            v = ld4(W_nc + (size_t)(k * 4 + s) * 256 + (row >> 1) * 128 + c4 * 4);
        }
        st4(wlds + k * 512 + f * 4, v);
    }
    __syncthreads();

    const int b    = blockIdx.x * 16 + (tid >> 5);
    const int lane = tid & 31;
    const int d0   = lane * 4;

    floatx4 Mv[COLS], Sv[COLS];
    #pragma unroll
    for (int i = 0; i < COLS; ++i) {
        const int fi = features[i * BATCH + b];
        Mv[i] = ld4(emb_mean + ((size_t)(i * NUM_EMB + fi)) * D + d0);
        const floatx4 s = ld4(emb_std + ((size_t)(i * NUM_EMB + fi)) * D + d0);
        floatx4 sp;
        sp.x = softplus01(s.x);
        sp.y = softplus01(s.y);
        sp.z = softplus01(s.z);
        sp.w = softplus01(s.w);
        Sv[i] = sp;
    }

    constexpr int PI[NPAIRS] = {0,0,0,0,0,0,0, 1,1,1,1,1,1, 2,2,2,2,2, 3,3,3,3, 4,4,4, 5,5, 6};
    constexpr int PJ[NPAIRS] = {1,2,3,4,5,6,7, 2,3,4,5,6,7, 3,4,5,6,7, 4,5,6,7, 5,6,7, 6,7, 7};

    const float* nrow = noise + (size_t)b * D + d0;
    constexpr size_t KSTRIDE = (size_t)2 * BATCH * D;
    constexpr size_t HSTRIDE = (size_t)BATCH * D;

    floatx4 nb0[2], nb1[2];
    nb0[0] = ld4(nrow);
    nb1[0] = ld4(nrow + HSTRIDE);

    float acc0 = 0.0f, acc1 = 0.0f;

    #pragma unroll
    for (int k = 0; k < NPAIRS; ++k) {
        const int buf = k & 1;
        const int nxt = buf ^ 1;

        if (k + 1 < NPAIRS) {
            nb0[nxt] = ld4(nrow + (size_t)(k + 1) * KSTRIDE);
            nb1[nxt] = ld4(nrow + (size_t)(k + 1) * KSTRIDE + HSTRIDE);
        }

        const int i = PI[k];
        const int j = PJ[k];
        const floatx4 n0 = nb0[buf];
        const floatx4 n1 = nb1[buf];
        const floatx4 p = Mv[i] + Sv[i] * n0;
        const floatx4 q = Mv[j] + Sv[j] * n1;

        const int    s  = __builtin_amdgcn_readfirstlane(pos_s[k]);
        const float* wk = wlds + k * 512 + d0;

        if (s == 4) {
            const floatx4 A0 = ld4(wk);
            const floatx4 B0 = ld4(wk + 128);
            const floatx4 A1 = ld4(wk + 256);
            const floatx4 B1 = ld4(wk + 384);
            acc0 += dot4(p, A0) + dot4(q, B0);
            acc1 += dot4(p, A1) + dot4(q, B1);
        } else {
            floatx4 c;
            if (s == 0) {
                c = p + q;
            } else if (s == 1) {
                c = p * q;
            } else if (s == 2) {
                c.x = fmaxf(p.x, q.x); c.y = fmaxf(p.y, q.y);
                c.z = fmaxf(p.z, q.z); c.w = fmaxf(p.w, q.w);
            } else {
                c.x = fminf(p.x, q.x); c.y = fminf(p.y, q.y);
                c.z = fminf(p.z, q.z); c.w = fminf(p.w, q.w);
            }
            const floatx4 W0 = ld4(wk);
            const floatx4 W1 = ld4(wk + 256);
            acc0 += dot4(c, W0);
            acc1 += dot4(c, W1);
        }
    }

    #pragma unroll
    for (int m = 16; m >= 1; m >>= 1) {
        acc0 += __shfl_xor(acc0, m, 64);
        acc1 += __shfl_xor(acc1, m, 64);
    }

    if (lane == 0) {
        float2 r; r.x = acc0; r.y = acc1;
        *reinterpret_cast<float2*>(out + b * 2) = r;
    }
}

// ===== Read-ceiling probe (profilable: ~940 MB of reads, > fill duration) =====
// 4 passes over the whole noise array, unit-stride grid-stride, 4-deep
// independent dwordx4 loads, 2048 blocks x 256 thr = 32 waves/CU.
// Per-wave reduce -> PLAIN STORE to a distinct d_ws slot (no atomics!).
// Passes 2-4 are L3-resident -> measures the same regime as timed replays.
__global__ __launch_bounds__(256) void read_probe(
    const float* __restrict__ noise, float* __restrict__ ws, long long n4)
{
    const long long stride = (long long)gridDim.x * blockDim.x;  // 524288
    float s = 0.0f;
    #pragma unroll 1
    for (int pass = 0; pass < 4; ++pass) {
        long long i = (long long)blockIdx.x * blockDim.x + threadIdx.x;
        // n4 = 14,680,064 = 28 * stride -> exactly 7 four-deep chunks
        for (; i + 3 * stride < n4; i += 4 * stride) {
            const floatx4 v0 = ld4(noise + 4 * i);
            const floatx4 v1 = ld4(noise + 4 * (i + stride));
            const floatx4 v2 = ld4(noise + 4 * (i + 2 * stride));
            const floatx4 v3 = ld4(noise + 4 * (i + 3 * stride));
            s += (v0.x + v0.y + v0.z + v0.w) + (v1.x + v1.y + v1.z + v1.w)
               + (v2.x + v2.y + v2.z + v2.w) + (v3.x + v3.y + v3.z + v3.w);
        }
        for (; i < n4; i += stride) {
            const floatx4 v = ld4(noise + 4 * i);
            s += v.x + v.y + v.z + v.w;
        }
    }
    #pragma unroll
    for (int m = 32; m >= 1; m >>= 1) s += __shfl_xor(s, m, 64);
    const int gwave = (int)(((long long)blockIdx.x * blockDim.x + threadIdx.x) >> 6);
    if ((threadIdx.x & 63) == 0) ws[gwave] = s;   // 8192 floats, distinct slots
}

extern "C" void kernel_launch(void* const* d_in, const int* in_sizes, int n_in,
                              void* d_out, int out_size, void* d_ws, size_t ws_size,
                              hipStream_t stream) {
    const int*   features  = (const int*)  d_in[0];
    const float* emb_mean  = (const float*)d_in[1];
    const float* emb_std   = (const float*)d_in[2];
    const float* W_nc      = (const float*)d_in[3];
    const float* W_cat     = (const float*)d_in[4];
    const float* log_alpha = (const float*)d_in[5];
    const float* noise     = (const float*)d_in[6];
    float*       out       = (float*)d_out;

    dim3 grid(BATCH / 16);  // 512 blocks
    dim3 block(512);        // 8 waves, 16 batch rows/block
    dsnas_kernel<<<grid, block, 0, stream>>>(features, emb_mean, emb_std,
                                             W_nc, W_cat, log_alpha, noise, out);

    // Read-ceiling probe; its dispatch should appear in rocprof top-5.
    const long long n4 = (long long)NPAIRS * 2 * BATCH * D / 4;  // 14,680,064
    read_probe<<<dim3(2048), dim3(256), 0, stream>>>(noise, (float*)d_ws, n4);
}

// Round 14
// 75.644 us; speedup vs baseline: 2.5973x; 2.5973x over previous
//
#include <hip/hip_runtime.h>

// Problem constants (from reference)
constexpr int COLS    = 8;
constexpr int BATCH   = 8192;
constexpr int D       = 128;
constexpr int NUM_EMB = 12;
constexpr int NPAIRS  = 28;

typedef float floatx4 __attribute__((ext_vector_type(4)));

__device__ __forceinline__ floatx4 ld4(const float* p) {
    return *reinterpret_cast<const floatx4*>(p);
}
__device__ __forceinline__ void st4(float* p, floatx4 v) {
    *reinterpret_cast<floatx4*>(p) = v;
}
__device__ __forceinline__ float softplus01(float x) {
    return 0.01f * ((x > 15.0f) ? x : log1pf(expf(x)));
}
__device__ __forceinline__ float dot4(floatx4 a, floatx4 b) {
    return fmaf(a.x, b.x, fmaf(a.y, b.y, fmaf(a.z, b.z, a.w * b.w)));
}

constexpr size_t KSTRIDE = (size_t)2 * BATCH * D;  // noise stride between pairs
constexpr size_t HSTRIDE = (size_t)BATCH * D;      // noise stride between halves

// R10's k-loop body, but iterating pairs in the rotated order (K0+t)%28.
// K0 is a template parameter so every index folds to a compile-time constant
// after unrolling (register-resident Mv/Sv stay register-resident). The
// branchy body is kept deliberately: it bounds scheduler load-hoisting and
// thus register pressure (the R4-R9 spill disease).
template<int K0>
__device__ __forceinline__ void run_rot(const float* __restrict__ nrow,
                                        const float* __restrict__ wk0,   // wlds + d0
                                        const int*   __restrict__ pos_s,
                                        const floatx4 (&Mv)[COLS],
                                        const floatx4 (&Sv)[COLS],
                                        float& acc0, float& acc1)
{
    constexpr int PI[NPAIRS] = {0,0,0,0,0,0,0, 1,1,1,1,1,1, 2,2,2,2,2, 3,3,3,3, 4,4,4, 5,5, 6};
    constexpr int PJ[NPAIRS] = {1,2,3,4,5,6,7, 2,3,4,5,6,7, 3,4,5,6,7, 4,5,6,7, 5,6,7, 6,7, 7};

    // Depth-1 double buffer exactly as R10 (t&1 indices, full unroll).
    floatx4 nb0[2], nb1[2];
    nb0[0] = ld4(nrow + (size_t)K0 * KSTRIDE);
    nb1[0] = ld4(nrow + (size_t)K0 * KSTRIDE + HSTRIDE);

    #pragma unroll
    for (int t = 0; t < NPAIRS; ++t) {
        const int k   = (K0 + t) % NPAIRS;       // folds to a literal per t
        const int kn  = (K0 + t + 1) % NPAIRS;
        const int buf = t & 1;
        const int nxt = buf ^ 1;

        // Prefetch the next pair's noise: the ONLY VMEM in this loop.
        if (t + 1 < NPAIRS) {
            nb0[nxt] = ld4(nrow + (size_t)kn * KSTRIDE);
            nb1[nxt] = ld4(nrow + (size_t)kn * KSTRIDE + HSTRIDE);
        }

        // Reparameterize (noise issued one iteration ago)
        const int i = PI[k];
        const int j = PJ[k];
        const floatx4 n0 = nb0[buf];
        const floatx4 n1 = nb1[buf];
        const floatx4 p = Mv[i] + Sv[i] * n0;    // Sv pre-scaled by 0.01
        const floatx4 q = Mv[j] + Sv[j] * n1;

        // Wave-uniform branch; weights from LDS only.
        const int    s  = __builtin_amdgcn_readfirstlane(pos_s[k]);
        const float* wk = wk0 + k * 512;

        if (s == 4) {
            const floatx4 A0 = ld4(wk);
            const floatx4 B0 = ld4(wk + 128);
            const floatx4 A1 = ld4(wk + 256);
            const floatx4 B1 = ld4(wk + 384);
            acc0 += dot4(p, A0) + dot4(q, B0);
            acc1 += dot4(p, A1) + dot4(q, B1);
        } else {
            floatx4 c;
            if (s == 0) {
                c = p + q;
            } else if (s == 1) {
                c = p * q;
            } else if (s == 2) {
                c.x = fmaxf(p.x, q.x); c.y = fmaxf(p.y, q.y);
                c.z = fmaxf(p.z, q.z); c.w = fmaxf(p.w, q.w);
            } else {
                c.x = fminf(p.x, q.x); c.y = fminf(p.y, q.y);
                c.z = fminf(p.z, q.z); c.w = fminf(p.w, q.w);
            }
            const floatx4 W0 = ld4(wk);
            const floatx4 W1 = ld4(wk + 256);
            acc0 += dot4(c, W0);
            acc1 += dot4(c, W1);
        }
    }
}

// Block = 512 threads = 8 waves; each 32-lane half-wave owns one batch row
// (16 rows/block, grid = 512). LDS weights (57 KB) -> 2 blocks/CU at the
// (512,4) VGPR cap: 16 waves/CU. Change vs R10: per-block k-order rotation
// (4 start points) to decorrelate the global noise-window access pattern.
__global__ __launch_bounds__(512, 4) void dsnas_kernel(
    const int*   __restrict__ features,   // [COLS, BATCH]
    const float* __restrict__ emb_mean,   // [COLS, NUM_EMB, D]
    const float* __restrict__ emb_std,    // [COLS, NUM_EMB, D]
    const float* __restrict__ W_nc,       // [NPAIRS, 4, 2, D]
    const float* __restrict__ W_cat,      // [NPAIRS, 2, 2*D]
    const float* __restrict__ log_alpha,  // [NPAIRS, 5]
    const float* __restrict__ noise,      // [NPAIRS, 2, BATCH, D]
    float*       __restrict__ out)        // [BATCH, 2]
{
    __shared__ float wlds[NPAIRS * 512];
    __shared__ int   pos_s[NPAIRS];

    const int tid = threadIdx.x;

    if (tid < NPAIRS) {
        const float* la = log_alpha + tid * 5;
        float best = la[0];
        int   bi   = 0;
        #pragma unroll
        for (int t = 1; t < 5; ++t) {
            float v = la[t];
            if (v > best) { best = v; bi = t; }
        }
        pos_s[tid] = bi;
    }
    __syncthreads();

    // Stage selected weights into LDS (512 threads cooperatively).
    #pragma unroll
    for (int r = 0; r < 7; ++r) {
        const int idx = tid + r * 512;
        const int k   = idx >> 7;
        const int f   = idx & 127;
        const int row = f >> 5;
        const int c4  = f & 31;
        const int s   = pos_s[k];
        floatx4 v = {0.0f, 0.0f, 0.0f, 0.0f};
        if (s == 4) {
            v = ld4(W_cat + (size_t)k * 512 + f * 4);
        } else if ((row & 1) == 0) {
            v = ld4(W_nc + (size_t)(k * 4 + s) * 256 + (row >> 1) * 128 + c4 * 4);
        }
        st4(wlds + k * 512 + f * 4, v);
    }
    __syncthreads();

    const int b    = blockIdx.x * 16 + (tid >> 5);
    const int lane = tid & 31;
    const int d0   = lane * 4;

    floatx4 Mv[COLS], Sv[COLS];
    #pragma unroll
    for (int i = 0; i < COLS; ++i) {
        const int fi = features[i * BATCH + b];
        Mv[i] = ld4(emb_mean + ((size_t)(i * NUM_EMB + fi)) * D + d0);
        const floatx4 s = ld4(emb_std + ((size_t)(i * NUM_EMB + fi)) * D + d0);
        floatx4 sp;
        sp.x = softplus01(s.x);
        sp.y = softplus01(s.y);
        sp.z = softplus01(s.z);
        sp.w = softplus01(s.w);
        Sv[i] = sp;
    }

    const float* nrow = noise + (size_t)b * D + d0;
    const float* wk0  = wlds + d0;

    float acc0 = 0.0f, acc1 = 0.0f;

    // Per-block k-order rotation: 4 start points spread the instantaneous
    // global access pattern over 4 window groups instead of 1.
    const int rot = blockIdx.x & 3;
    if (rot == 0) {
        run_rot<0>(nrow, wk0, pos_s, Mv, Sv, acc0, acc1);
    } else if (rot == 1) {
        run_rot<7>(nrow, wk0, pos_s, Mv, Sv, acc0, acc1);
    } else if (rot == 2) {
        run_rot<14>(nrow, wk0, pos_s, Mv, Sv, acc0, acc1);
    } else {
        run_rot<21>(nrow, wk0, pos_s, Mv, Sv, acc0, acc1);
    }

    // Reduce across the 32 lanes of this half-wave
    #pragma unroll
    for (int m = 16; m >= 1; m >>= 1) {
        acc0 += __shfl_xor(acc0, m, 64);
        acc1 += __shfl_xor(acc1, m, 64);
    }

    if (lane == 0) {
        float2 r; r.x = acc0; r.y = acc1;
        *reinterpret_cast<float2*>(out + b * 2) = r;
    }
}

extern "C" void kernel_launch(void* const* d_in, const int* in_sizes, int n_in,
                              void* d_out, int out_size, void* d_ws, size_t ws_size,
                              hipStream_t stream) {
    const int*   features  = (const int*)  d_in[0];
    const float* emb_mean  = (const float*)d_in[1];
    const float* emb_std   = (const float*)d_in[2];
    const float* W_nc      = (const float*)d_in[3];
    const float* W_cat     = (const float*)d_in[4];
    const float* log_alpha = (const float*)d_in[5];
    const float* noise     = (const float*)d_in[6];
    float*       out       = (float*)d_out;

    dim3 grid(BATCH / 16);  // 512 blocks
    dim3 block(512);        // 8 waves, 16 batch rows/block
    dsnas_kernel<<<grid, block, 0, stream>>>(features, emb_mean, emb_std,
                                             W_nc, W_cat, log_alpha, noise, out);
}

// Round 15
// 49.728 us; speedup vs baseline: 3.9510x; 1.5212x over previous
//
#include <hip/hip_runtime.h>

// Problem constants (from reference)
constexpr int COLS    = 8;
constexpr int BATCH   = 8192;
constexpr int D       = 128;
constexpr int NUM_EMB = 12;
constexpr int NPAIRS  = 28;

constexpr int CHUNKS        = 32;               // row-chunks per pair
constexpr int ROWS_PER_CHUNK = BATCH / CHUNKS;  // 256
constexpr size_t HSTRIDE = (size_t)BATCH * D;   // noise stride between halves

typedef float floatx4 __attribute__((ext_vector_type(4)));

__device__ const int PI_d[NPAIRS] = {0,0,0,0,0,0,0, 1,1,1,1,1,1, 2,2,2,2,2, 3,3,3,3, 4,4,4, 5,5, 6};
__device__ const int PJ_d[NPAIRS] = {1,2,3,4,5,6,7, 2,3,4,5,6,7, 3,4,5,6,7, 4,5,6,7, 5,6,7, 6,7, 7};

__device__ __forceinline__ floatx4 ld4(const float* p) {
    return *reinterpret_cast<const floatx4*>(p);
}
__device__ __forceinline__ void st4(float* p, floatx4 v) {
    *reinterpret_cast<floatx4*>(p) = v;
}
__device__ __forceinline__ float dot4(floatx4 a, floatx4 b) {
    return fmaf(a.x, b.x, fmaf(a.y, b.y, fmaf(a.z, b.z, a.w * b.w)));
}
__device__ __forceinline__ floatx4 vmax4(floatx4 a, floatx4 b) {
    floatx4 r; r.x=fmaxf(a.x,b.x); r.y=fmaxf(a.y,b.y); r.z=fmaxf(a.z,b.z); r.w=fmaxf(a.w,b.w); return r;
}
__device__ __forceinline__ floatx4 vmin4(floatx4 a, floatx4 b) {
    floatx4 r; r.x=fminf(a.x,b.x); r.y=fminf(a.y,b.y); r.z=fminf(a.z,b.z); r.w=fminf(a.w,b.w); return r;
}

// ===== Kernel 1: precompute 0.01*softplus(emb_std) into d_ws (once per call) =====
__global__ __launch_bounds__(256) void sp_kernel(const float* __restrict__ emb_std,
                                                 float* __restrict__ spstd)
{
    const int idx = blockIdx.x * 256 + threadIdx.x;   // float4 id, 3072 total
    if (idx < COLS * NUM_EMB * D / 4) {
        const floatx4 v = ld4(emb_std + 4 * idx);
        floatx4 r;
        r.x = 0.01f * ((v.x > 15.0f) ? v.x : log1pf(expf(v.x)));
        r.y = 0.01f * ((v.y > 15.0f) ? v.y : log1pf(expf(v.y)));
        r.z = 0.01f * ((v.z > 15.0f) ? v.z : log1pf(expf(v.z)));
        r.w = 0.01f * ((v.w > 15.0f) ? v.w : log1pf(expf(v.w)));
        st4(spstd + 4 * idx, r);
    }
}

// ===== Row loop, specialized per op S (block-uniform -> hoisted branch) =====
template<int S, bool ATOMIC>
__device__ __forceinline__ void row_loop(
    int k, int chunk, int halfid, int lane, int d0,
    const int* __restrict__ fI, const int* __restrict__ fJ,
    const float* __restrict__ miB, const float* __restrict__ siB,
    const float* __restrict__ mjB, const float* __restrict__ sjB,
    const float* __restrict__ nk0, const float* __restrict__ nk1,
    floatx4 A0, floatx4 B0, floatx4 A1, floatx4 B1,
    float* __restrict__ dst)
{
    #pragma unroll 2
    for (int r = 0; r < ROWS_PER_CHUNK / 8; ++r) {   // 8 rows per iteration
        const int b = chunk * ROWS_PER_CHUNK + r * 8 + halfid;

        // HBM stream (contiguous across the block): the long-latency loads.
        const floatx4 n0 = ld4(nk0 + (size_t)b * D);
        const floatx4 n1 = ld4(nk1 + (size_t)b * D);

        // L1/L2 gathers (overlap under the noise latency).
        const int fi = fI[b];
        const int fj = fJ[b];
        const floatx4 Mi = ld4(miB + fi * D);
        const floatx4 Si = ld4(siB + fi * D);
        const floatx4 Mj = ld4(mjB + fj * D);
        const floatx4 Sj = ld4(sjB + fj * D);

        const floatx4 p = Mi + Si * n0;   // S' pre-scaled by 0.01
        const floatx4 q = Mj + Sj * n1;

        float a0, a1;
        if constexpr (S == 4) {
            a0 = dot4(p, A0) + dot4(q, B0);
            a1 = dot4(p, A1) + dot4(q, B1);
        } else {
            floatx4 c;
            if constexpr (S == 0)      c = p + q;
            else if constexpr (S == 1) c = p * q;
            else if constexpr (S == 2) c = vmax4(p, q);
            else                       c = vmin4(p, q);
            a0 = dot4(c, A0);
            a1 = dot4(c, A1);
        }

        #pragma unroll
        for (int m = 16; m >= 1; m >>= 1) {
            a0 += __shfl_xor(a0, m, 64);
            a1 += __shfl_xor(a1, m, 64);
        }

        if (lane == 0) {
            if constexpr (ATOMIC) {
                atomicAdd(dst + b * 2 + 0, a0);
                atomicAdd(dst + b * 2 + 1, a1);
            } else {
                float2 r2; r2.x = a0; r2.y = a1;
                *reinterpret_cast<float2*>(dst + ((size_t)k * BATCH + b) * 2) = r2;
            }
        }
    }
}

// ===== Kernel 2: one (pair, row-chunk) per block. No LDS; ~60 VGPR live. =====
template<bool ATOMIC>
__global__ __launch_bounds__(256) void pair_kernel(
    const int*   __restrict__ features,   // [COLS, BATCH]
    const float* __restrict__ emb_mean,   // [COLS, NUM_EMB, D]
    const float* __restrict__ spstd,      // [COLS, NUM_EMB, D] (precomputed)
    const float* __restrict__ W_nc,       // [NPAIRS, 4, 2, D]
    const float* __restrict__ W_cat,      // [NPAIRS, 2, 2*D]
    const float* __restrict__ log_alpha,  // [NPAIRS, 5]
    const float* __restrict__ noise,      // [NPAIRS, 2, BATCH, D]
    float*       __restrict__ dst)        // partial [NPAIRS][BATCH][2] or out [BATCH][2]
{
    const int bid    = blockIdx.x;
    const int k      = bid >> 5;           // pair (CHUNKS = 32)
    const int chunk  = bid & (CHUNKS - 1);
    const int tid    = threadIdx.x;
    const int halfid = tid >> 5;           // 0..7: row within the 8-row iter
    const int lane   = tid & 31;
    const int d0     = lane * 4;

    // Routing: argmax over 5 (block-uniform; first-max wins)
    const float* la = log_alpha + k * 5;
    float best = la[0];
    int   s    = 0;
    #pragma unroll
    for (int t = 1; t < 5; ++t) {
        const float v = la[t];
        if (v > best) { best = v; s = t; }
    }

    // Selected weight rows into registers (block-uniform rows, per-lane d0).
    floatx4 A0 = {0,0,0,0}, B0 = {0,0,0,0}, A1 = {0,0,0,0}, B1 = {0,0,0,0};
    if (s == 4) {
        const float* wb = W_cat + (size_t)k * 512;
        A0 = ld4(wb + d0);       B0 = ld4(wb + 128 + d0);
        A1 = ld4(wb + 256 + d0); B1 = ld4(wb + 384 + d0);
    } else {
        const float* wb = W_nc + (size_t)(k * 4 + s) * 256;
        A0 = ld4(wb + d0);
        A1 = ld4(wb + 128 + d0);
    }

    const int i = PI_d[k];
    const int j = PJ_d[k];
    const int* fI = features + i * BATCH;
    const int* fJ = features + j * BATCH;
    const float* miB = emb_mean + (size_t)i * NUM_EMB * D + d0;
    const float* siB = spstd    + (size_t)i * NUM_EMB * D + d0;
    const float* mjB = emb_mean + (size_t)j * NUM_EMB * D + d0;
    const float* sjB = spstd    + (size_t)j * NUM_EMB * D + d0;
    const float* nk0 = noise + (size_t)(2 * k) * HSTRIDE + d0;
    const float* nk1 = nk0 + HSTRIDE;

    switch (s) {
        case 0: row_loop<0,ATOMIC>(k,chunk,halfid,lane,d0,fI,fJ,miB,siB,mjB,sjB,nk0,nk1,A0,B0,A1,B1,dst); break;
        case 1: row_loop<1,ATOMIC>(k,chunk,halfid,lane,d0,fI,fJ,miB,siB,mjB,sjB,nk0,nk1,A0,B0,A1,B1,dst); break;
        case 2: row_loop<2,ATOMIC>(k,chunk,halfid,lane,d0,fI,fJ,miB,siB,mjB,sjB,nk0,nk1,A0,B0,A1,B1,dst); break;
        case 3: row_loop<3,ATOMIC>(k,chunk,halfid,lane,d0,fI,fJ,miB,siB,mjB,sjB,nk0,nk1,A0,B0,A1,B1,dst); break;
        default:row_loop<4,ATOMIC>(k,chunk,halfid,lane,d0,fI,fJ,miB,siB,mjB,sjB,nk0,nk1,A0,B0,A1,B1,dst); break;
    }
}

// ===== Kernel 3a: deterministic fixed-order reduction over pairs =====
__global__ __launch_bounds__(256) void reduce_kernel(const float* __restrict__ partial,
                                                     float* __restrict__ out)
{
    const int idx = blockIdx.x * 256 + threadIdx.x;   // 0..16383
    float s = 0.0f;
    #pragma unroll
    for (int k = 0; k < NPAIRS; ++k) {
        s += partial[(size_t)k * (BATCH * 2) + idx];
    }
    out[idx] = s;
}

// ===== Kernel 3b (fallback): zero out before atomic accumulation =====
__global__ __launch_bounds__(256) void zero_kernel(float* __restrict__ out)
{
    const int idx = blockIdx.x * 256 + threadIdx.x;
    out[idx] = 0.0f;
}

extern "C" void kernel_launch(void* const* d_in, const int* in_sizes, int n_in,
                              void* d_out, int out_size, void* d_ws, size_t ws_size,
                              hipStream_t stream) {
    const int*   features  = (const int*)  d_in[0];
    const float* emb_mean  = (const float*)d_in[1];
    const float* emb_std   = (const float*)d_in[2];
    const float* W_nc      = (const float*)d_in[3];
    const float* W_cat     = (const float*)d_in[4];
    const float* log_alpha = (const float*)d_in[5];
    const float* noise     = (const float*)d_in[6];
    float*       out       = (float*)d_out;

    float* spstd   = (float*)d_ws;                         // 12288 floats
    float* partial = spstd + COLS * NUM_EMB * D;           // 28*8192*2 floats
    const size_t need_bytes = (size_t)(COLS * NUM_EMB * D + NPAIRS * BATCH * 2) * 4;

    // 1) precompute 0.01*softplus(emb_std)
    sp_kernel<<<dim3(12), dim3(256), 0, stream>>>(emb_std, spstd);

    if (ws_size >= need_bytes) {
        // 2) pair-major streaming kernel -> partials
        pair_kernel<false><<<dim3(NPAIRS * CHUNKS), dim3(256), 0, stream>>>(
            features, emb_mean, spstd, W_nc, W_cat, log_alpha, noise, partial);
        // 3) deterministic reduce over pairs
        reduce_kernel<<<dim3(BATCH * 2 / 256), dim3(256), 0, stream>>>(partial, out);
    } else {
        // Fallback: zero + atomic accumulation directly into out
        zero_kernel<<<dim3(BATCH * 2 / 256), dim3(256), 0, stream>>>(out);
        pair_kernel<true><<<dim3(NPAIRS * CHUNKS), dim3(256), 0, stream>>>(
            features, emb_mean, spstd, W_nc, W_cat, log_alpha, noise, out);
    }
}